// Round 9
// baseline (179.146 us; speedup 1.0000x reference)
//
#include <hip/hip_runtime.h>

#define N_IN 8192
#define N_H 8192
#define THRV 1.0f
#define BETA 0.9f
#define PI_F 3.14159265358979323846f

typedef float f32x4 __attribute__((ext_vector_type(4)));
typedef float f32x2 __attribute__((ext_vector_type(2)));

// ws layout (float elements):
// [0      .. 8191 ]  gpos
// [8192   .. 16383]  gneg
// [24576  .. 32763]  itv  (2047 f32x4, byte off 98304, 16B aligned)
// [32768  .. 32771]  it4 = {it[0], it[1], it[2], it[8191]}
// [32772  .. 36867]  part: 2048 blocks x f32x2 {l, c} (byte off 131088)

__global__ __launch_bounds__(256) void k_matvec(
        const float* __restrict__ W,
        const float* __restrict__ inp,
        const float* __restrict__ mem,
        const float* __restrict__ spk_trace,
        const float* __restrict__ prediction,
        const float* __restrict__ neg_trace,
        const float* __restrict__ inp_trace,
        float* __restrict__ out,
        float* __restrict__ gpos,
        float* __restrict__ gneg,
        f32x4* __restrict__ itv,
        float* __restrict__ it4,
        f32x2* __restrict__ part) {
    const int wave = threadIdx.x >> 6;
    const int lane = threadIdx.x & 63;
    const int row  = blockIdx.x * 4 + wave;
    const f32x4* __restrict__ Wr = (const f32x4*)(W + (size_t)row * N_IN);
    const f32x4* __restrict__ I4 = (const f32x4*)inp;
    double acc0 = 0.0, acc1 = 0.0;
#pragma unroll 8
    for (int k = 0; k < 32; k += 2) {
        f32x4 wa = Wr[lane + 64 * k];
        f32x4 xa = I4[lane + 64 * k];
        f32x4 wb = Wr[lane + 64 * (k + 1)];
        f32x4 xb = I4[lane + 64 * (k + 1)];
        acc0 += (double)wa.x * xa.x + (double)wa.y * xa.y
              + (double)wa.z * xa.z + (double)wa.w * xa.w;
        acc1 += (double)wb.x * xb.x + (double)wb.y * xb.y
              + (double)wb.z * xb.z + (double)wb.w * xb.w;
    }
    double acc = acc0 + acc1;
#pragma unroll
    for (int off = 32; off; off >>= 1)
        acc += __shfl_down(acc, off, 64);

    __shared__ double sl[4], sc[4];
    if (lane == 0) {
        float c  = (float)acc;
        float m  = mem[row];
        float reset = (m > THRV) ? 1.0f : 0.0f;
        float mn = BETA * m + c - reset * THRV;
        float spk = (mn > THRV) ? 1.0f : 0.0f;
        float st  = spk_trace[row] + spk / 10.0f;
        float pr  = prediction[row];
        float ng  = neg_trace[row];
        out[row]       = spk;
        out[N_H + row] = st;
        float x = PI_F * (mn - THRV);
        float surr = 1.0f / (PI_F * (1.0f + x * x));
        gpos[row] = (pr - st) * surr;
        gneg[row] = (ng - st) * surr;
        double dl = (double)(st - pr);
        double dc = (double)(ng - pr);
        sl[wave] = dl * dl;
        sc[wave] = dc * dc;
    }
    if (lane == 32) {
        if (wave == 0 && blockIdx.x < 2047) {
            const int i0 = 4 * blockIdx.x + 3;
            f32x4 v;
            v.x = inp_trace[i0]     + inp[i0]     / 10.0f;
            v.y = inp_trace[i0 + 1] + inp[i0 + 1] / 10.0f;
            v.z = inp_trace[i0 + 2] + inp[i0 + 2] / 10.0f;
            v.w = inp_trace[i0 + 3] + inp[i0 + 3] / 10.0f;
            itv[blockIdx.x] = v;
        }
        if (wave == 1 && blockIdx.x == 0) {
            it4[0] = inp_trace[0]    + inp[0]    / 10.0f;
            it4[1] = inp_trace[1]    + inp[1]    / 10.0f;
            it4[2] = inp_trace[2]    + inp[2]    / 10.0f;
            it4[3] = inp_trace[8191] + inp[8191] / 10.0f;
        }
    }
    __syncthreads();
    if (threadIdx.x == 0) {
        f32x2 p;
        p.x = (float)(sl[0] + sl[1] + sl[2] + sl[3]);
        p.y = (float)(sc[0] + sc[1] + sc[2] + sc[3]);
        part[blockIdx.x] = p;
    }
}

// Every block redundantly reduces the 2048 partial pairs in a FIXED order
// (bit-identical gates in all blocks, no atomics/fences), then streams its
// slice of dW with nontemporal stores (no L2 write-allocate).
// NOTE: fully idempotent (reads only ws, writes only out) — launched twice
// this round purely to measure T_outer from the total duration delta.
__global__ __launch_bounds__(256) void k_outer(
        const float* __restrict__ gpos,
        const float* __restrict__ gneg,
        const f32x2* __restrict__ part,
        const f32x4* __restrict__ itv,
        const float* __restrict__ it4,
        float* __restrict__ out) {
    __shared__ float wl[4], wc[4];
    {
        const int t = threadIdx.x;
        float l = 0.0f, c = 0.0f;
#pragma unroll
        for (int k = 0; k < 8; ++k) {
            f32x2 p = part[t * 8 + k];
            l += p.x; c += p.y;
        }
#pragma unroll
        for (int off = 32; off; off >>= 1) {
            l += __shfl_down(l, off, 64);
            c += __shfl_down(c, off, 64);
        }
        if ((t & 63) == 0) { wl[t >> 6] = l; wc[t >> 6] = c; }
    }
    __syncthreads();
    const float lsum = (wl[0] + wl[1]) + (wl[2] + wl[3]);
    const float csum = (wc[0] + wc[1]) + (wc[2] + wc[3]);
    // loss = lsum ; loss_c = -csum
    const float ga = (lsum > 20.0f)  ? 1.0f : 0.0f;
    const float gb = (csum < 100.0f) ? 1.0f : 0.0f;

    const long long NV = 16777215LL;   // aligned f32x4 stores in dW region
    long long t = (long long)blockIdx.x * 256 + threadIdx.x;
    const long long stride = (long long)gridDim.x * 256;
    for (; t < NV; t += stride) {
        long long d = 3 + 4 * t;           // dW flat element index
        int h = (int)(d >> 13);
        int i = (int)(d & 8191);           // i == 3 (mod 4)
        float ch = ga * gpos[h] - gb * gneg[h];
        f32x4 v;
        if (i != 8191) {
            f32x4 iv = itv[i >> 2];
            v.x = ch * iv.x; v.y = ch * iv.y; v.z = ch * iv.z; v.w = ch * iv.w;
        } else {                            // straddles row boundary
            float c2 = ga * gpos[h + 1] - gb * gneg[h + 1];
            v.x = ch * it4[3]; v.y = c2 * it4[0]; v.z = c2 * it4[1]; v.w = c2 * it4[2];
        }
        __builtin_nontemporal_store(v, (f32x4*)(out + 16388 + 4 * t));
    }
    if (blockIdx.x == 0 && threadIdx.x == 0) {
        float c0 = ga * gpos[0] - gb * gneg[0];
        float cL = ga * gpos[8191] - gb * gneg[8191];
        out[16385] = c0 * it4[0];
        out[16386] = c0 * it4[1];
        out[16387] = c0 * it4[2];
        out[67125248] = cL * it4[3];   // dW[8191][8191]
        out[2 * N_H]  = (lsum - csum) * 0.5f;
    }
}

extern "C" void kernel_launch(void* const* d_in, const int* in_sizes, int n_in,
                              void* d_out, int out_size, void* d_ws, size_t ws_size,
                              hipStream_t stream) {
    const float* inp       = (const float*)d_in[0];
    const float* mem       = (const float*)d_in[1];
    const float* spk_trace = (const float*)d_in[2];
    const float* inp_trace = (const float*)d_in[3];
    const float* pred      = (const float*)d_in[4];
    const float* neg       = (const float*)d_in[5];
    const float* W         = (const float*)d_in[6];
    float* out = (float*)d_out;

    float*  wsf  = (float*)d_ws;
    float*  gpos = wsf;
    float*  gneg = wsf + 8192;
    f32x4*  itv  = (f32x4*)(wsf + 24576);
    float*  it4  = wsf + 32768;
    f32x2*  part = (f32x2*)(wsf + 32772);

    k_matvec<<<N_H / 4, 256, 0, stream>>>(W, inp, mem, spk_trace, pred, neg,
                                          inp_trace, out, gpos, gneg, itv, it4,
                                          part);
    // MEASUREMENT: k_outer launched twice (idempotent). dur - R8_dur ≈ T_outer.
    k_outer<<<4096, 256, 0, stream>>>(gpos, gneg, part, itv, it4, out);
    k_outer<<<4096, 256, 0, stream>>>(gpos, gneg, part, itv, it4, out);
}

// Round 10
// 111.389 us; speedup vs baseline: 1.6083x; 1.6083x over previous
//
#include <hip/hip_runtime.h>

#define N_IN 8192
#define N_H 8192
#define THRV 1.0f
#define BETA 0.9f
#define PI_F 3.14159265358979323846f

typedef float f32x4 __attribute__((ext_vector_type(4)));
typedef float f32x2 __attribute__((ext_vector_type(2)));

// ws layout (float elements):
// [0      .. 8191 ]  gpos
// [8192   .. 16383]  gneg
// [24576  .. 32763]  itv  (2047 f32x4, byte off 98304, 16B aligned)
// [32768  .. 32771]  it4 = {it[0], it[1], it[2], it[8191]}
// [32772  .. 36867]  part: 2048 blocks x f32x2 {l, c} (byte off 131088)

__global__ __launch_bounds__(256) void k_matvec(
        const float* __restrict__ W,
        const float* __restrict__ inp,
        const float* __restrict__ mem,
        const float* __restrict__ spk_trace,
        const float* __restrict__ prediction,
        const float* __restrict__ neg_trace,
        const float* __restrict__ inp_trace,
        float* __restrict__ out,
        float* __restrict__ gpos,
        float* __restrict__ gneg,
        f32x4* __restrict__ itv,
        float* __restrict__ it4,
        f32x2* __restrict__ part) {
    const int wave = threadIdx.x >> 6;
    const int lane = threadIdx.x & 63;
    const int row  = blockIdx.x * 4 + wave;
    const f32x4* __restrict__ Wr = (const f32x4*)(W + (size_t)row * N_IN);
    const f32x4* __restrict__ I4 = (const f32x4*)inp;
    double acc0 = 0.0, acc1 = 0.0;
#pragma unroll 8
    for (int k = 0; k < 32; k += 2) {
        f32x4 wa = Wr[lane + 64 * k];
        f32x4 xa = I4[lane + 64 * k];
        f32x4 wb = Wr[lane + 64 * (k + 1)];
        f32x4 xb = I4[lane + 64 * (k + 1)];
        acc0 += (double)wa.x * xa.x + (double)wa.y * xa.y
              + (double)wa.z * xa.z + (double)wa.w * xa.w;
        acc1 += (double)wb.x * xb.x + (double)wb.y * xb.y
              + (double)wb.z * xb.z + (double)wb.w * xb.w;
    }
    double acc = acc0 + acc1;
#pragma unroll
    for (int off = 32; off; off >>= 1)
        acc += __shfl_down(acc, off, 64);

    __shared__ double sl[4], sc[4];
    if (lane == 0) {
        float c  = (float)acc;
        float m  = mem[row];
        float reset = (m > THRV) ? 1.0f : 0.0f;
        float mn = BETA * m + c - reset * THRV;
        float spk = (mn > THRV) ? 1.0f : 0.0f;
        float st  = spk_trace[row] + spk / 10.0f;
        float pr  = prediction[row];
        float ng  = neg_trace[row];
        out[row]       = spk;
        out[N_H + row] = st;
        float x = PI_F * (mn - THRV);
        float surr = 1.0f / (PI_F * (1.0f + x * x));
        gpos[row] = (pr - st) * surr;
        gneg[row] = (ng - st) * surr;
        double dl = (double)(st - pr);
        double dc = (double)(ng - pr);
        sl[wave] = dl * dl;
        sc[wave] = dc * dc;
    }
    if (lane == 32) {
        if (wave == 0 && blockIdx.x < 2047) {
            const int i0 = 4 * blockIdx.x + 3;
            f32x4 v;
            v.x = inp_trace[i0]     + inp[i0]     / 10.0f;
            v.y = inp_trace[i0 + 1] + inp[i0 + 1] / 10.0f;
            v.z = inp_trace[i0 + 2] + inp[i0 + 2] / 10.0f;
            v.w = inp_trace[i0 + 3] + inp[i0 + 3] / 10.0f;
            itv[blockIdx.x] = v;
        }
        if (wave == 1 && blockIdx.x == 0) {
            it4[0] = inp_trace[0]    + inp[0]    / 10.0f;
            it4[1] = inp_trace[1]    + inp[1]    / 10.0f;
            it4[2] = inp_trace[2]    + inp[2]    / 10.0f;
            it4[3] = inp_trace[8191] + inp[8191] / 10.0f;
        }
    }
    __syncthreads();
    if (threadIdx.x == 0) {
        f32x2 p;
        p.x = (float)(sl[0] + sl[1] + sl[2] + sl[3]);
        p.y = (float)(sc[0] + sc[1] + sc[2] + sc[3]);
        part[blockIdx.x] = p;
    }
}

// Row-walker: block b owns rows [4b, 4b+4). Each thread holds its 8 itv
// quads in REGISTERS (loaded once), then per row fires 8 NT stores of
// coef[r] * q[k]. Gates via redundant fixed-order reduce (no atomics).
__global__ __launch_bounds__(256) void k_outer(
        const float* __restrict__ gpos,
        const float* __restrict__ gneg,
        const f32x2* __restrict__ part,
        const f32x4* __restrict__ itv,
        const float* __restrict__ it4,
        float* __restrict__ out) {
    const int t = threadIdx.x;
    const bool lastt = (t == 255);

    // itv quads -> registers (j = t + 256k; j == 2047 doesn't exist)
    f32x4 q[8];
#pragma unroll
    for (int k = 0; k < 8; ++k) {
        const int j = t + 256 * k;
        if (j < 2047) q[k] = itv[j];
    }
    float e0 = 0.f, e1 = 0.f, e2 = 0.f, e3 = 0.f;
    if (lastt || (blockIdx.x == 0 && t == 0)) {
        e0 = it4[0]; e1 = it4[1]; e2 = it4[2]; e3 = it4[3];
    }

    // gates prologue (deterministic, bit-identical in every block)
    __shared__ float wl[4], wc[4];
    {
        float l = 0.0f, c = 0.0f;
#pragma unroll
        for (int k = 0; k < 8; ++k) {
            f32x2 p = part[t * 8 + k];
            l += p.x; c += p.y;
        }
#pragma unroll
        for (int off = 32; off; off >>= 1) {
            l += __shfl_down(l, off, 64);
            c += __shfl_down(c, off, 64);
        }
        if ((t & 63) == 0) { wl[t >> 6] = l; wc[t >> 6] = c; }
    }
    __syncthreads();
    const float lsum = (wl[0] + wl[1]) + (wl[2] + wl[3]);
    const float csum = (wc[0] + wc[1]) + (wc[2] + wc[3]);
    // loss = lsum ; loss_c = -csum
    const float ga = (lsum > 20.0f)  ? 1.0f : 0.0f;
    const float gb = (csum < 100.0f) ? 1.0f : 0.0f;

    const int r0 = blockIdx.x * 4;
#pragma unroll
    for (int rr = 0; rr < 4; ++rr) {
        const int r = r0 + rr;
        const float cr = ga * gpos[r] - gb * gneg[r];
        float* rowp = out + 16388 + (size_t)r * 8192;
#pragma unroll
        for (int k = 0; k < 7; ++k) {
            f32x4 v = q[k];
            v.x *= cr; v.y *= cr; v.z *= cr; v.w *= cr;
            __builtin_nontemporal_store(v, (f32x4*)(rowp + 4 * (t + 256 * k)));
        }
        if (!lastt) {
            f32x4 v = q[7];
            v.x *= cr; v.y *= cr; v.z *= cr; v.w *= cr;
            __builtin_nontemporal_store(v, (f32x4*)(rowp + 4 * (t + 1792)));
        } else if (r < 8191) {      // row-crossing vector {r:8191, r+1:0,1,2}
            const float cn = ga * gpos[r + 1] - gb * gneg[r + 1];
            f32x4 v;
            v.x = cr * e3; v.y = cn * e0; v.z = cn * e1; v.w = cn * e2;
            __builtin_nontemporal_store(v, (f32x4*)(rowp + 4 * 2047));
        } else {                    // very last element, scalar
            out[67125248] = cr * e3;
        }
    }
    if (blockIdx.x == 0 && t == 0) {
        const float c0 = ga * gpos[0] - gb * gneg[0];
        out[16385] = c0 * e0;
        out[16386] = c0 * e1;
        out[16387] = c0 * e2;
        out[2 * N_H] = (lsum - csum) * 0.5f;
    }
}

extern "C" void kernel_launch(void* const* d_in, const int* in_sizes, int n_in,
                              void* d_out, int out_size, void* d_ws, size_t ws_size,
                              hipStream_t stream) {
    const float* inp       = (const float*)d_in[0];
    const float* mem       = (const float*)d_in[1];
    const float* spk_trace = (const float*)d_in[2];
    const float* inp_trace = (const float*)d_in[3];
    const float* pred      = (const float*)d_in[4];
    const float* neg       = (const float*)d_in[5];
    const float* W         = (const float*)d_in[6];
    float* out = (float*)d_out;

    float*  wsf  = (float*)d_ws;
    float*  gpos = wsf;
    float*  gneg = wsf + 8192;
    f32x4*  itv  = (f32x4*)(wsf + 24576);
    float*  it4  = wsf + 32768;
    f32x2*  part = (f32x2*)(wsf + 32772);

    k_matvec<<<N_H / 4, 256, 0, stream>>>(W, inp, mem, spk_trace, pred, neg,
                                          inp_trace, out, gpos, gneg, itv, it4,
                                          part);
    k_outer<<<2048, 256, 0, stream>>>(gpos, gneg, part, itv, it4, out);
}

// Round 11
// 93.291 us; speedup vs baseline: 1.9203x; 1.1940x over previous
//
#include <hip/hip_runtime.h>

#define N_IN 8192
#define N_H 8192
#define THRV 1.0f
#define BETA 0.9f
#define PI_F 3.14159265358979323846f

typedef float f32x4 __attribute__((ext_vector_type(4)));
typedef float f32x2 __attribute__((ext_vector_type(2)));

// ws layout (float elements):
// [0      .. 8191 ]  gpos
// [8192   .. 16383]  gneg
// [24576  .. 32763]  itv  (2047 f32x4, byte off 98304, 16B aligned)
// [32768  .. 32771]  it4 = {it[0], it[1], it[2], it[8191]}
// [32772  .. 36867]  part: 2048 blocks x f32x2 {l, c} (byte off 131088)

__global__ __launch_bounds__(256) void k_matvec(
        const float* __restrict__ W,
        const float* __restrict__ inp,
        const float* __restrict__ mem,
        const float* __restrict__ spk_trace,
        const float* __restrict__ prediction,
        const float* __restrict__ neg_trace,
        const float* __restrict__ inp_trace,
        float* __restrict__ out,
        float* __restrict__ gpos,
        float* __restrict__ gneg,
        f32x4* __restrict__ itv,
        float* __restrict__ it4,
        f32x2* __restrict__ part) {
    const int wave = threadIdx.x >> 6;
    const int lane = threadIdx.x & 63;
    const int row  = blockIdx.x * 4 + wave;
    const f32x4* __restrict__ Wr = (const f32x4*)(W + (size_t)row * N_IN);
    const f32x4* __restrict__ I4 = (const f32x4*)inp;
    double acc0 = 0.0, acc1 = 0.0;
#pragma unroll 8
    for (int k = 0; k < 32; k += 2) {
        f32x4 wa = Wr[lane + 64 * k];
        f32x4 xa = I4[lane + 64 * k];
        f32x4 wb = Wr[lane + 64 * (k + 1)];
        f32x4 xb = I4[lane + 64 * (k + 1)];
        acc0 += (double)wa.x * xa.x + (double)wa.y * xa.y
              + (double)wa.z * xa.z + (double)wa.w * xa.w;
        acc1 += (double)wb.x * xb.x + (double)wb.y * xb.y
              + (double)wb.z * xb.z + (double)wb.w * xb.w;
    }
    double acc = acc0 + acc1;
#pragma unroll
    for (int off = 32; off; off >>= 1)
        acc += __shfl_down(acc, off, 64);

    __shared__ double sl[4], sc[4];
    if (lane == 0) {
        float c  = (float)acc;
        float m  = mem[row];
        float reset = (m > THRV) ? 1.0f : 0.0f;
        float mn = BETA * m + c - reset * THRV;
        float spk = (mn > THRV) ? 1.0f : 0.0f;
        float st  = spk_trace[row] + spk / 10.0f;
        float pr  = prediction[row];
        float ng  = neg_trace[row];
        out[row]       = spk;
        out[N_H + row] = st;
        float x = PI_F * (mn - THRV);
        float surr = 1.0f / (PI_F * (1.0f + x * x));
        gpos[row] = (pr - st) * surr;
        gneg[row] = (ng - st) * surr;
        double dl = (double)(st - pr);
        double dc = (double)(ng - pr);
        sl[wave] = dl * dl;
        sc[wave] = dc * dc;
    }
    if (lane == 32) {
        if (wave == 0 && blockIdx.x < 2047) {
            const int i0 = 4 * blockIdx.x + 3;
            f32x4 v;
            v.x = inp_trace[i0]     + inp[i0]     / 10.0f;
            v.y = inp_trace[i0 + 1] + inp[i0 + 1] / 10.0f;
            v.z = inp_trace[i0 + 2] + inp[i0 + 2] / 10.0f;
            v.w = inp_trace[i0 + 3] + inp[i0 + 3] / 10.0f;
            itv[blockIdx.x] = v;
        }
        if (wave == 1 && blockIdx.x == 0) {
            it4[0] = inp_trace[0]    + inp[0]    / 10.0f;
            it4[1] = inp_trace[1]    + inp[1]    / 10.0f;
            it4[2] = inp_trace[2]    + inp[2]    / 10.0f;
            it4[3] = inp_trace[8191] + inp[8191] / 10.0f;
        }
    }
    __syncthreads();
    if (threadIdx.x == 0) {
        f32x2 p;
        p.x = (float)(sl[0] + sl[1] + sl[2] + sl[3]);
        p.y = (float)(sc[0] + sc[1] + sc[2] + sc[3]);
        part[blockIdx.x] = p;
    }
}

// Grid-stride dW writer. Bulk starts at element 16400 (byte 65600, 64B
// cache-line aligned; row stride 32KB keeps every wave span line-aligned).
// Gates via redundant fixed-order reduce (no atomics/fences).
__global__ __launch_bounds__(256) void k_outer(
        const float* __restrict__ gpos,
        const float* __restrict__ gneg,
        const f32x2* __restrict__ part,
        const f32x4* __restrict__ itv,
        const float* __restrict__ it4,
        float* __restrict__ out) {
    __shared__ float wl[4], wc[4];
    {
        const int t = threadIdx.x;
        float l = 0.0f, c = 0.0f;
#pragma unroll
        for (int k = 0; k < 8; ++k) {
            f32x2 p = part[t * 8 + k];
            l += p.x; c += p.y;
        }
#pragma unroll
        for (int off = 32; off; off >>= 1) {
            l += __shfl_down(l, off, 64);
            c += __shfl_down(c, off, 64);
        }
        if ((t & 63) == 0) { wl[t >> 6] = l; wc[t >> 6] = c; }
    }
    __syncthreads();
    const float lsum = (wl[0] + wl[1]) + (wl[2] + wl[3]);
    const float csum = (wc[0] + wc[1]) + (wc[2] + wc[3]);
    // loss = lsum ; loss_c = -csum
    const float ga = (lsum > 20.0f)  ? 1.0f : 0.0f;
    const float gb = (csum < 100.0f) ? 1.0f : 0.0f;

    const long long NV = 16777212LL;   // 64B-aligned f32x4 stores
    long long t = (long long)blockIdx.x * 256 + threadIdx.x;
    const long long stride = (long long)gridDim.x * 256;
    for (; t < NV; t += stride) {
        long long d = 15 + 4 * t;          // dW flat element index
        int h = (int)(d >> 13);
        int i = (int)(d & 8191);           // i == 3 (mod 4)
        float ch = ga * gpos[h] - gb * gneg[h];
        f32x4 v;
        if (i != 8191) {
            f32x4 iv = itv[(i - 3) >> 2];
            v.x = ch * iv.x; v.y = ch * iv.y; v.z = ch * iv.z; v.w = ch * iv.w;
        } else {                            // straddles row boundary
            float c2 = ga * gpos[h + 1] - gb * gneg[h + 1];
            v.x = ch * it4[3]; v.y = c2 * it4[0]; v.z = c2 * it4[1]; v.w = c2 * it4[2];
        }
        __builtin_nontemporal_store(v, (f32x4*)(out + 16400 + 4 * t));
    }
    if (blockIdx.x == 0 && threadIdx.x == 0) {
        const float c0 = ga * gpos[0] - gb * gneg[0];
        const float cL = ga * gpos[8191] - gb * gneg[8191];
        // head: row 0 cols 0..14 (elements 16385..16399)
        out[16385] = c0 * it4[0];
        out[16386] = c0 * it4[1];
        out[16387] = c0 * it4[2];
        f32x4 a = itv[0], b = itv[1], c = itv[2];   // it[3..6], it[7..10], it[11..14]
        out[16388] = c0 * a.x; out[16389] = c0 * a.y;
        out[16390] = c0 * a.z; out[16391] = c0 * a.w;
        out[16392] = c0 * b.x; out[16393] = c0 * b.y;
        out[16394] = c0 * b.z; out[16395] = c0 * b.w;
        out[16396] = c0 * c.x; out[16397] = c0 * c.y;
        out[16398] = c0 * c.z; out[16399] = c0 * c.w;
        out[67125248] = cL * it4[3];   // dW[8191][8191]
        out[2 * N_H]  = (lsum - csum) * 0.5f;
    }
}

extern "C" void kernel_launch(void* const* d_in, const int* in_sizes, int n_in,
                              void* d_out, int out_size, void* d_ws, size_t ws_size,
                              hipStream_t stream) {
    const float* inp       = (const float*)d_in[0];
    const float* mem       = (const float*)d_in[1];
    const float* spk_trace = (const float*)d_in[2];
    const float* inp_trace = (const float*)d_in[3];
    const float* pred      = (const float*)d_in[4];
    const float* neg       = (const float*)d_in[5];
    const float* W         = (const float*)d_in[6];
    float* out = (float*)d_out;

    float*  wsf  = (float*)d_ws;
    float*  gpos = wsf;
    float*  gneg = wsf + 8192;
    f32x4*  itv  = (f32x4*)(wsf + 24576);
    float*  it4  = wsf + 32768;
    f32x2*  part = (f32x2*)(wsf + 32772);

    k_matvec<<<N_H / 4, 256, 0, stream>>>(W, inp, mem, spk_trace, pred, neg,
                                          inp_trace, out, gpos, gneg, itv, it4,
                                          part);
    k_outer<<<4096, 256, 0, stream>>>(gpos, gneg, part, itv, it4, out);
}